// Round 1
// baseline (82390.918 us; speedup 1.0000x reference)
//
#include <hip/hip_runtime.h>
#include <hip/hip_bf16.h>

#define NEGV (-1e30f)

constexpr int B_    = 32;
constexpr int T_    = 500;
constexpr int D_    = 3072;
constexpr int S_DEN = 4000;
constexpr int E_DEN = 120000;
constexpr int S_NUM = 200;
constexpr int E_NUM = 600;
constexpr int NT    = 1024;   // threads per chain block
constexpr int NWAVE = NT / 64;

// ---- pack edges into int4 {src, dst, pdf, logw-bits} ----------------------
__global__ void pack_edges(const int* __restrict__ src, const int* __restrict__ dst,
                           const int* __restrict__ pdf, const float* __restrict__ logw,
                           int4* __restrict__ out, int n) {
    int i = blockIdx.x * blockDim.x + threadIdx.x;
    if (i < n) out[i] = make_int4(src[i], dst[i], pdf[i], __float_as_int(logw[i]));
}

// ---- one block per chain: blocks [0,32) = den, [32,64) = num --------------
template<bool PACKED>
__global__ __launch_bounds__(NT)
void chain_forward(const float* __restrict__ x, const int* __restrict__ x_lengths,
                   const int* __restrict__ den_src, const int* __restrict__ den_dst,
                   const int* __restrict__ den_pdf, const float* __restrict__ den_logw,
                   const float* __restrict__ den_init, const float* __restrict__ den_final,
                   const int* __restrict__ num_src, const int* __restrict__ num_dst,
                   const int* __restrict__ num_pdf, const float* __restrict__ num_logw,
                   const float* __restrict__ num_init, const float* __restrict__ num_final,
                   const int4* __restrict__ den_pk, const int4* __restrict__ num_pk,
                   float* __restrict__ ll_out) {
    __shared__ float a_rel[S_DEN];   // alpha - running offset (max ~ 0)
    __shared__ float ssum[S_DEN];    // per-dst accumulation of exp(score)
    __shared__ float xrow[D_];       // x[b, t, :]
    __shared__ float red[NWAVE];
    __shared__ float s_m;

    const int  tid    = threadIdx.x;
    const bool is_den = blockIdx.x < B_;
    const int  b      = is_den ? blockIdx.x : blockIdx.x - B_;
    const int  S      = is_den ? S_DEN : S_NUM;
    const int  E      = is_den ? E_DEN : E_NUM;

    const int*   esrc;  const int* edst;  const int* epdf;  const float* elogw;
    const int4*  epk;
    const float* init;  const float* fin;
    if (is_den) {
        esrc = den_src; edst = den_dst; epdf = den_pdf; elogw = den_logw;
        epk  = den_pk;
        init = den_init; fin = den_final;
    } else {
        esrc = num_src + b * E_NUM; edst = num_dst + b * E_NUM;
        epdf = num_pdf + b * E_NUM; elogw = num_logw + b * E_NUM;
        epk  = num_pk + b * E_NUM;
        init = num_init + b * S_NUM; fin = num_final + b * S_NUM;
    }
    const int    len = x_lengths[b];
    const float* xb  = x + (size_t)b * T_ * D_;

    for (int s = tid; s < S; s += NT) { a_rel[s] = init[s]; ssum[s] = 0.f; }
    float off = 0.f;

    for (int t = 0; t < len; ++t) {
        // stage x[b,t,:] (float4, coalesced)
        const float4* xr4 = reinterpret_cast<const float4*>(xb + (size_t)t * D_);
        for (int d = tid; d < D_ / 4; d += NT)
            reinterpret_cast<float4*>(xrow)[d] = xr4[d];
        __syncthreads();

        // edge pass: ssum[dst] += exp(a_rel[src] + logw + x[t,pdf])
        if (PACKED) {
            for (int e = tid; e < E; e += NT) {
                int4 p = epk[e];
                float v = a_rel[p.x] + __int_as_float(p.w) + xrow[p.z];
                atomicAdd(&ssum[p.y], __expf(v));
            }
        } else {
            for (int e = tid; e < E; e += NT) {
                float v = a_rel[esrc[e]] + elogw[e] + xrow[epdf[e]];
                atomicAdd(&ssum[edst[e]], __expf(v));
            }
        }
        __syncthreads();

        // alpha update + renormalize: a_rel = log(ssum) - m,  off += m
        float lm = -3.0e38f;
        for (int s = tid; s < S; s += NT) {
            float v  = ssum[s];
            float nr = (v > 0.f) ? __logf(v) : NEGV;
            a_rel[s] = nr;
            lm = fmaxf(lm, nr);
        }
        #pragma unroll
        for (int o = 32; o > 0; o >>= 1) lm = fmaxf(lm, __shfl_down(lm, o));
        if ((tid & 63) == 0) red[tid >> 6] = lm;
        __syncthreads();
        if (tid == 0) {
            float m = red[0];
            #pragma unroll
            for (int w = 1; w < NWAVE; ++w) m = fmaxf(m, red[w]);
            if (m < -1e29f) m = 0.f;   // all-dead guard
            s_m = m;
        }
        __syncthreads();
        float m = s_m;
        off += m;
        for (int s = tid; s < S; s += NT) { a_rel[s] -= m; ssum[s] = 0.f; }
        // no barrier needed: next-iteration stage/barrier orders a_rel/ssum
    }

    // ll = off + log( sum_s exp(a_rel[s] + final[s]) )   (a_rel <= 0, no overflow)
    float lsum = 0.f;
    for (int s = tid; s < S; s += NT) lsum += __expf(a_rel[s] + fin[s]);
    #pragma unroll
    for (int o = 32; o > 0; o >>= 1) lsum += __shfl_down(lsum, o);
    if ((tid & 63) == 0) red[tid >> 6] = lsum;
    __syncthreads();
    if (tid == 0) {
        float tot = 0.f;
        #pragma unroll
        for (int w = 0; w < NWAVE; ++w) tot += red[w];
        ll_out[blockIdx.x] = off + __logf(tot);
    }
}

// ---- combine: objf = (sum den_ll - sum num_ll) / sum(lengths) -------------
__global__ void finalize_loss(const float* __restrict__ ll, const int* __restrict__ x_lengths,
                              float* __restrict__ out) {
    int tid = threadIdx.x;              // 64 threads, 1 block
    float d = (tid < B_) ? ll[tid] : 0.f;
    float n = (tid < B_) ? ll[B_ + tid] : 0.f;
    float l = (tid < B_) ? (float)x_lengths[tid] : 0.f;
    #pragma unroll
    for (int o = 32; o > 0; o >>= 1) {
        d += __shfl_down(d, o);
        n += __shfl_down(n, o);
        l += __shfl_down(l, o);
    }
    if (tid == 0) out[0] = (d - n) / l;
}

extern "C" void kernel_launch(void* const* d_in, const int* in_sizes, int n_in,
                              void* d_out, int out_size, void* d_ws, size_t ws_size,
                              hipStream_t stream) {
    const float* x         = (const float*)d_in[0];
    const int*   x_lengths = (const int*)  d_in[1];
    const int*   den_src   = (const int*)  d_in[2];
    const int*   den_dst   = (const int*)  d_in[3];
    const int*   den_pdf   = (const int*)  d_in[4];
    const float* den_logw  = (const float*)d_in[5];
    const float* den_init  = (const float*)d_in[6];
    const float* den_final = (const float*)d_in[7];
    const int*   num_src   = (const int*)  d_in[8];
    const int*   num_dst   = (const int*)  d_in[9];
    const int*   num_pdf   = (const int*)  d_in[10];
    const float* num_logw  = (const float*)d_in[11];
    const float* num_init  = (const float*)d_in[12];
    const float* num_final = (const float*)d_in[13];

    float* ll = (float*)d_ws;                                   // 64 floats
    int4*  den_pk = (int4*)((char*)d_ws + 256);
    int4*  num_pk = den_pk + E_DEN;
    size_t need = 256 + (size_t)(E_DEN + B_ * E_NUM) * sizeof(int4);

    if (ws_size >= need) {
        pack_edges<<<(E_DEN + 255) / 256, 256, 0, stream>>>(
            den_src, den_dst, den_pdf, den_logw, den_pk, E_DEN);
        pack_edges<<<(B_ * E_NUM + 255) / 256, 256, 0, stream>>>(
            num_src, num_dst, num_pdf, num_logw, num_pk, B_ * E_NUM);
        chain_forward<true><<<2 * B_, NT, 0, stream>>>(
            x, x_lengths, den_src, den_dst, den_pdf, den_logw, den_init, den_final,
            num_src, num_dst, num_pdf, num_logw, num_init, num_final,
            den_pk, num_pk, ll);
    } else {
        chain_forward<false><<<2 * B_, NT, 0, stream>>>(
            x, x_lengths, den_src, den_dst, den_pdf, den_logw, den_init, den_final,
            num_src, num_dst, num_pdf, num_logw, num_init, num_final,
            den_pk, num_pk, ll);
    }
    finalize_loss<<<1, 64, 0, stream>>>(ll, x_lengths, (float*)d_out);
}